// Round 13
// baseline (498.701 us; speedup 1.0000x reference)
//
#include <hip/hip_runtime.h>
#include <hip/hip_bf16.h>

#define DD 64
#define SCAN_CH 1024
#define MST 68      // fallback fp32 stride
#define MSTE 66     // bf16 tile stride (elems)
#define NBLK_P 1024
#define BUK_BITS 12

typedef __attribute__((ext_vector_type(8))) short bf16x8;
typedef __attribute__((ext_vector_type(4))) float f32x4;
typedef unsigned long long u64;

__device__ __forceinline__ unsigned short f2bf(float f) {
    unsigned int u = __float_as_uint(f);
    unsigned int r = (u + 0x7fffu + ((u >> 16) & 1u)) >> 16;   // RNE
    return (unsigned short)r;
}
__device__ __forceinline__ float bf2f(unsigned short u) {
    return __uint_as_float((unsigned int)u << 16);
}
__device__ __forceinline__ unsigned int pack2(float lo, float hi) {
    return (unsigned int)f2bf(lo) | ((unsigned int)f2bf(hi) << 16);
}
__device__ __forceinline__ unsigned int cvt_pk_bf16(float lo, float hi) {
    unsigned int r;
    asm("v_cvt_pk_bf16_f32 %0, %1, %2" : "=v"(r) : "v"(lo), "v"(hi));
    return r;
}
__device__ __forceinline__ unsigned short f2bf1(float v) {   // 1-instr bf16 (RNE)
    return (unsigned short)cvt_pk_bf16(v, v);
}
__device__ __forceinline__ unsigned int prod2(unsigned int a, unsigned int b) {
    const float la = __uint_as_float(a << 16);
    const float ha = __uint_as_float(a & 0xffff0000u);
    const float lb = __uint_as_float(b << 16);
    const float hb = __uint_as_float(b & 0xffff0000u);
    return cvt_pk_bf16(la * lb, ha * hb);
}
__device__ __forceinline__ void pk_atomic_add_bf16(unsigned short* addr, unsigned int data) {
    asm volatile("global_atomic_pk_add_bf16 %0, %1, off" :: "v"(addr), "v"(data) : "memory");
}

// B frag for 16x16x32: lane l holds B[k = ks*32 + (l>>4)*8 + b][col = nt*16 + (l&15)]
__device__ __forceinline__ void load_w_frags(const float* __restrict__ W, int lane,
                                             bf16x8 bw[4][2]) {
    const int kl = (lane >> 4) * 8;
    const int cl = lane & 15;
#pragma unroll
    for (int nt = 0; nt < 4; ++nt)
#pragma unroll
        for (int ks = 0; ks < 2; ++ks)
#pragma unroll
            for (int b = 0; b < 8; ++b)
                bw[nt][ks][b] = (short)f2bf(W[(ks * 32 + kl + b) * DD + nt * 16 + cl]);
}

#define MFMA8(BW, A0, A1)                                                        \
    acc0 = __builtin_amdgcn_mfma_f32_16x16x32_bf16(A0, BW[0][0], acc0, 0, 0, 0); \
    acc0 = __builtin_amdgcn_mfma_f32_16x16x32_bf16(A1, BW[0][1], acc0, 0, 0, 0); \
    acc1 = __builtin_amdgcn_mfma_f32_16x16x32_bf16(A0, BW[1][0], acc1, 0, 0, 0); \
    acc1 = __builtin_amdgcn_mfma_f32_16x16x32_bf16(A1, BW[1][1], acc1, 0, 0, 0); \
    acc2 = __builtin_amdgcn_mfma_f32_16x16x32_bf16(A0, BW[2][0], acc2, 0, 0, 0); \
    acc2 = __builtin_amdgcn_mfma_f32_16x16x32_bf16(A1, BW[2][1], acc2, 0, 0, 0); \
    acc3 = __builtin_amdgcn_mfma_f32_16x16x32_bf16(A0, BW[3][0], acc3, 0, 0, 0); \
    acc3 = __builtin_amdgcn_mfma_f32_16x16x32_bf16(A1, BW[3][1], acc3, 0, 0, 0);

// ---------- x-table prep + LDS-private coarse histogram (fused) ----------
__global__ __launch_bounds__(256) void xprep_hist2_kernel(
    const float4* __restrict__ feat4, const float4* __restrict__ emb4,
    const int* __restrict__ rel, unsigned short* __restrict__ xtab, int n4,
    const int* __restrict__ ac, unsigned int* __restrict__ gtab,
    int T_, int chunk, int NBUK) {
    __shared__ unsigned int lc[256];
    const int b = blockIdx.x, tid = threadIdx.x;
    lc[tid] = 0;
    __syncthreads();
    const int lo = b * chunk, hi = min(lo + chunk, T_);
    for (int t = lo + tid; t < hi; t += 256) atomicAdd(&lc[ac[t] >> BUK_BITS], 1u);
    __syncthreads();
    for (int i = tid; i < NBUK; i += 256) gtab[i * NBLK_P + b] = lc[i];

    const int tid0   = b * 256 + tid;
    const int stride = gridDim.x * 256;
    for (int i = tid0; i < n4; i += stride) {
        const int e  = i >> 4;
        const int re = rel[e];
        const float4 f = feat4[i];
        const float4 g = emb4[re * 16 + (i & 15)];
        ushort4 o;
        o.x = f2bf(f.x + g.x); o.y = f2bf(f.y + g.y);
        o.z = f2bf(f.z + g.z); o.w = f2bf(f.w + g.w);
        *reinterpret_cast<ushort4*>(&xtab[(size_t)i * 4]) = o;
    }
}

// ---------- scan over gtab (n = NBUK*NBLK_P) ----------
__global__ __launch_bounds__(256) void scanA_kernel(const unsigned int* __restrict__ cnt,
                                                    unsigned int* __restrict__ bsum, int n) {
    __shared__ unsigned int s[256];
    const int b = blockIdx.x, tid = threadIdx.x;
    const int base = b * SCAN_CH + tid * 4;
    unsigned int v = 0;
#pragma unroll
    for (int k = 0; k < 4; ++k) { const int i = base + k; if (i < n) v += cnt[i]; }
    s[tid] = v; __syncthreads();
    for (int off = 128; off > 0; off >>= 1) {
        if (tid < off) s[tid] += s[tid + off];
        __syncthreads();
    }
    if (tid == 0) bsum[b] = s[0];
}

__global__ __launch_bounds__(1024) void scanB_kernel(unsigned int* bsum, int nb) {
    __shared__ unsigned int s[1024];
    const int tid = threadIdx.x;
    s[tid] = (tid < nb) ? bsum[tid] : 0u;
    __syncthreads();
    for (int off = 1; off < 1024; off <<= 1) {
        const unsigned int t = (tid >= off) ? s[tid - off] : 0u;
        __syncthreads();
        s[tid] += t;
        __syncthreads();
    }
    if (tid < nb) bsum[tid] = (tid == 0) ? 0u : s[tid - 1];   // exclusive
}

__global__ __launch_bounds__(256) void scanC_kernel(const unsigned int* __restrict__ cnt,
                                                    const unsigned int* __restrict__ bsum,
                                                    unsigned int* __restrict__ offs, int n) {
    __shared__ unsigned int s[256];
    const int b = blockIdx.x, tid = threadIdx.x;
    const int base = b * SCAN_CH + tid * 4;
    unsigned int v[4], sum = 0;
#pragma unroll
    for (int k = 0; k < 4; ++k) { const int i = base + k; v[k] = (i < n) ? cnt[i] : 0u; sum += v[k]; }
    s[tid] = sum; __syncthreads();
    for (int off = 1; off < 256; off <<= 1) {
        const unsigned int t = (tid >= off) ? s[tid - off] : 0u;
        __syncthreads();
        s[tid] += t;
        __syncthreads();
    }
    unsigned int run = bsum[b] + (s[tid] - sum);
#pragma unroll
    for (int k = 0; k < 4; ++k) { const int i = base + k; if (i < n) offs[i] = run; run += v[k]; }
}

// ---------- partition into buckets (packed 8B) ----------
__global__ __launch_bounds__(256) void part_kernel(
    const int* __restrict__ ab, const int* __restrict__ bc, const int* __restrict__ ac,
    const unsigned int* __restrict__ gtabO, u64* __restrict__ tep,
    int T_, int chunk, int NBUK) {
    __shared__ unsigned int cur[256];
    const int b = blockIdx.x, tid = threadIdx.x;
    for (int i = tid; i < NBUK; i += 256) cur[i] = gtabO[i * NBLK_P + b];
    __syncthreads();
    const int lo = b * chunk, hi = min(lo + chunk, T_);
    for (int t = lo + tid; t < hi; t += 256) {
        const int e = ac[t];
        const unsigned int pos = atomicAdd(&cur[e >> BUK_BITS], 1u);
        tep[pos] = (u64)(unsigned)ab[t] | ((u64)(unsigned)bc[t] << 20) | ((u64)(unsigned)e << 40);
    }
}

// ---------- per-bucket LDS counting sort ----------
__global__ __launch_bounds__(256) void lsort_kernel(
    const u64* __restrict__ tep, const unsigned int* __restrict__ gtabO,
    u64* __restrict__ teps, int T_, int NBUK) {
    __shared__ unsigned int cnt4[1 << BUK_BITS];   // 16 KB
    __shared__ unsigned int part[256];
    const int buk = blockIdx.x, tid = threadIdx.x;
    const int s0 = (int)gtabO[buk * NBLK_P];
    const int s1 = (buk + 1 < NBUK) ? (int)gtabO[(buk + 1) * NBLK_P] : T_;
    const int n  = s1 - s0;

    for (int i = tid; i < (1 << BUK_BITS); i += 256) cnt4[i] = 0;
    __syncthreads();
    for (int i = tid; i < n; i += 256) {
        const int elo = (int)((tep[s0 + i] >> 40) & ((1u << BUK_BITS) - 1));
        atomicAdd(&cnt4[elo], 1u);
    }
    __syncthreads();
    unsigned int s = 0;
#pragma unroll
    for (int k = 0; k < 16; ++k) s += cnt4[tid * 16 + k];
    part[tid] = s;
    __syncthreads();
    for (int off = 1; off < 256; off <<= 1) {
        const unsigned int t = (tid >= off) ? part[tid - off] : 0u;
        __syncthreads();
        part[tid] += t;
        __syncthreads();
    }
    unsigned int run = (tid ? part[tid - 1] : 0u);
#pragma unroll
    for (int k = 0; k < 16; ++k) {
        const unsigned int c = cnt4[tid * 16 + k];
        cnt4[tid * 16 + k] = run;
        run += c;
    }
    __syncthreads();
    for (int i = tid; i < n; i += 256) {
        const u64 v  = tep[s0 + i];
        const int elo = (int)((v >> 40) & ((1u << BUK_BITS) - 1));
        const unsigned int pos = atomicAdd(&cnt4[elo], 1u);
        teps[s0 + pos] = v;
    }
}

// ---------- fused CSR message+reduce (bf16 M tile: 16.6 KB LDS -> 8 blocks/CU) ----------
__global__ __launch_bounds__(256, 8) void tri_csr5_kernel(
    const unsigned short* __restrict__ xtab, const float* __restrict__ Wmsg,
    const u64* __restrict__ tep, unsigned short* __restrict__ aggbf,
    int T_, int S) {
    __shared__ unsigned short P[4][16 * 64];      // 8 KB
    __shared__ unsigned short M[4][16 * MSTE];    // 8.4 KB (bf16 messages)

    const int lane = threadIdx.x & 63;
    const int w    = threadIdx.x >> 6;

    bf16x8 bw[4][2];
    load_w_frags(Wmsg, lane, bw);

    const int gw = (blockIdx.x * blockDim.x + threadIdx.x) >> 6;
    const int p0 = gw * S;
    if (p0 >= T_) return;
    const int p1 = min(p0 + S, T_);

    const int rh = lane >> 3;
    const int cb = (lane & 7) * 8;

    int cur_e = -1; float sum = 0.f;
    int e_sv  = -1; float sum_sv = 0.f;
    bool have_sv = false;

    for (int t0 = p0; t0 < p1; t0 += 16) {
        const int cnt = min(16, p1 - t0);
        const u64 tq = tep[t0 + min(lane & 15, cnt - 1)];
        const int pa = (int)(tq & 0xFFFFFu);
        const int pb = (int)((tq >> 20) & 0xFFFFFu);
        const int pe = (int)(tq >> 40);

#pragma unroll
        for (int half = 0; half < 2; ++half) {
            const int ttl = half * 8 + rh;
            const int eA  = __shfl(pa, ttl, 64);
            const int eB  = __shfl(pb, ttl, 64);
            const uint4 va = *reinterpret_cast<const uint4*>(&xtab[(size_t)eA * DD + cb]);
            const uint4 vb = *reinterpret_cast<const uint4*>(&xtab[(size_t)eB * DD + cb]);
            uint4 pk;
            pk.x = prod2(va.x, vb.x);
            pk.y = prod2(va.y, vb.y);
            pk.z = prod2(va.z, vb.z);
            pk.w = prod2(va.w, vb.w);
            const int swz = (ttl & 7) << 3;
            *reinterpret_cast<uint4*>(&P[w][ttl * 64 + (cb ^ swz)]) = pk;
        }

        const int row = lane & 15;
        const int d0  = (lane >> 4) * 8;
        const int sw  = (row & 7) << 3;
        const bf16x8 a0 = *reinterpret_cast<const bf16x8*>(&P[w][row * 64 + ((d0)      ^ sw)]);
        const bf16x8 a1 = *reinterpret_cast<const bf16x8*>(&P[w][row * 64 + ((d0 + 32) ^ sw)]);

        f32x4 acc0 = {0.f, 0.f, 0.f, 0.f}, acc1 = acc0, acc2 = acc0, acc3 = acc0;
        MFMA8(bw, a0, a1)

        const int rb4 = (lane >> 4) * 4;
        const int cl  = lane & 15;
#pragma unroll
        for (int r = 0; r < 4; ++r) {
            M[w][(rb4 + r) * MSTE + cl + 0]  = f2bf1(fmaxf(acc0[r], 0.f));
            M[w][(rb4 + r) * MSTE + cl + 16] = f2bf1(fmaxf(acc1[r], 0.f));
            M[w][(rb4 + r) * MSTE + cl + 32] = f2bf1(fmaxf(acc2[r], 0.f));
            M[w][(rb4 + r) * MSTE + cl + 48] = f2bf1(fmaxf(acc3[r], 0.f));
        }

        for (int r = 0; r < cnt; ++r) {
            const int e_r = __builtin_amdgcn_readlane(pe, r);
            if (e_r != cur_e) {
                if (cur_e >= 0) {
                    if (!have_sv) { e_sv = cur_e; sum_sv = sum; have_sv = true; }
                    else aggbf[(size_t)cur_e * DD + lane] = f2bf(sum);  // exclusive owner
                }
                cur_e = e_r; sum = 0.f;
            }
            sum += bf2f(M[w][r * MSTE + lane]);
        }
    }

    // boundary edges -> pk-atomics onto memset-zeroed aggbf
    {
        const float nsum = __shfl_xor(sum, 1, 64);
        if (cur_e >= 0 && !(lane & 1))
            pk_atomic_add_bf16(&aggbf[(size_t)cur_e * DD + lane], pack2(sum, nsum));
        if (have_sv) {
            const float nsv = __shfl_xor(sum_sv, 1, 64);
            if (!(lane & 1))
                pk_atomic_add_bf16(&aggbf[(size_t)e_sv * DD + lane], pack2(sum_sv, nsv));
        }
    }
}

// ---------- update pass (bf16 U tile: 16.6 KB LDS -> 8 blocks/CU) ----------
__global__ __launch_bounds__(256, 8) void upd_fast2(
    const unsigned short* __restrict__ xtab, const unsigned short* __restrict__ aggbf,
    const float* __restrict__ Wupd, float* __restrict__ out, int E_) {
    __shared__ unsigned short P[4][16 * 64];
    __shared__ unsigned short U[4][16 * MSTE];

    const int lane = threadIdx.x & 63;
    const int w    = threadIdx.x >> 6;

    bf16x8 bw[4][2];
    load_w_frags(Wupd, lane, bw);

    const int wave   = (blockIdx.x * blockDim.x + threadIdx.x) >> 6;
    const int nwaves = (gridDim.x * blockDim.x) >> 6;
    const int groups = E_ >> 4;

    for (int g = wave; g < groups; g += nwaves) {
        const int bu = g << 4;

#pragma unroll
        for (int half = 0; half < 2; ++half) {
            const int flat = half * 512 + lane * 8;
            const int row  = flat >> 6;
            const int colb = flat & 63;
            const uint4 v = *reinterpret_cast<const uint4*>(&aggbf[(size_t)bu * DD + flat]);
            *reinterpret_cast<uint4*>(&P[w][row * 64 + (colb ^ ((row & 7) << 3))]) = v;
        }

        const int row = lane & 15;
        const int d0  = (lane >> 4) * 8;
        const int sw  = (row & 7) << 3;
        const bf16x8 a0 = *reinterpret_cast<const bf16x8*>(&P[w][row * 64 + ((d0)      ^ sw)]);
        const bf16x8 a1 = *reinterpret_cast<const bf16x8*>(&P[w][row * 64 + ((d0 + 32) ^ sw)]);

        f32x4 acc0 = {0.f, 0.f, 0.f, 0.f}, acc1 = acc0, acc2 = acc0, acc3 = acc0;
        MFMA8(bw, a0, a1)

        const int rb4 = (lane >> 4) * 4;
        const int cl  = lane & 15;
#pragma unroll
        for (int r = 0; r < 4; ++r) {
            U[w][(rb4 + r) * MSTE + cl + 0]  = f2bf1(acc0[r]);
            U[w][(rb4 + r) * MSTE + cl + 16] = f2bf1(acc1[r]);
            U[w][(rb4 + r) * MSTE + cl + 32] = f2bf1(acc2[r]);
            U[w][(rb4 + r) * MSTE + cl + 48] = f2bf1(acc3[r]);
        }

#pragma unroll
        for (int tt = 0; tt < 16; ++tt) {
            const int e   = bu + tt;
            const float x = bf2f(xtab[(size_t)e * DD + lane]);
            out[(size_t)e * DD + lane] = fmaxf(x + bf2f(U[w][tt * MSTE + lane]), 0.f);
        }
    }
}

// ---------- tier 1: fully general fallback ----------
__global__ __launch_bounds__(256) void tri_fb(
    const float* __restrict__ feat, const float* __restrict__ emb,
    const float* __restrict__ Wmsg, const int* __restrict__ rel,
    const int* __restrict__ ab, const int* __restrict__ bc,
    const int* __restrict__ ac, float* __restrict__ agg, int T_) {
    __shared__ unsigned short P[4][16 * 64];
    const int lane = threadIdx.x & 63;
    const int w    = threadIdx.x >> 6;
    bf16x8 bw[4][2];
    load_w_frags(Wmsg, lane, bw);
    const int wave   = (blockIdx.x * blockDim.x + threadIdx.x) >> 6;
    const int nwaves = (gridDim.x * blockDim.x) >> 6;
    const int groups = (T_ + 15) >> 4;
    for (int g = wave; g < groups; g += nwaves) {
        const int bu = __builtin_amdgcn_readfirstlane(g << 4);
#pragma unroll 4
        for (int tt = 0; tt < 16; ++tt) {
            const int t = bu + tt;
            float p = 0.f;
            if (t < T_) {
                const int ea = ab[t], eb = bc[t];
                const float xa = feat[ea * DD + lane] + emb[rel[ea] * DD + lane];
                const float xb = feat[eb * DD + lane] + emb[rel[eb] * DD + lane];
                p = xa * xb;
            }
            P[w][tt * 64 + (lane ^ ((tt & 7) << 3))] = f2bf(p);
        }
        const int row = lane & 15;
        const int d0  = (lane >> 4) * 8;
        const int sw  = (row & 7) << 3;
        const bf16x8 a0 = *reinterpret_cast<const bf16x8*>(&P[w][row * 64 + ((d0)      ^ sw)]);
        const bf16x8 a1 = *reinterpret_cast<const bf16x8*>(&P[w][row * 64 + ((d0 + 32) ^ sw)]);
        f32x4 acc0 = {0.f, 0.f, 0.f, 0.f}, acc1 = acc0, acc2 = acc0, acc3 = acc0;
        MFMA8(bw, a0, a1)
        const int rb4 = (lane >> 4) * 4;
        const int cl  = lane & 15;
#pragma unroll
        for (int r = 0; r < 4; ++r) {
            const int t = bu + rb4 + r;
            if (t < T_) {
                float* dst = &agg[(size_t)ac[t] * DD + cl];
                atomicAdd(dst + 0,  fmaxf(acc0[r], 0.f));
                atomicAdd(dst + 16, fmaxf(acc1[r], 0.f));
                atomicAdd(dst + 32, fmaxf(acc2[r], 0.f));
                atomicAdd(dst + 48, fmaxf(acc3[r], 0.f));
            }
        }
    }
}

__global__ __launch_bounds__(256) void upd_fb(
    const float* __restrict__ feat, const float* __restrict__ emb,
    const float* __restrict__ Wupd, const int* __restrict__ rel,
    float* __restrict__ agg_out, int E_) {
    __shared__ unsigned short P[4][16 * 64];
    __shared__ float U[4][16 * MST];
    const int lane = threadIdx.x & 63;
    const int w    = threadIdx.x >> 6;
    bf16x8 bw[4][2];
    load_w_frags(Wupd, lane, bw);
    const int wave   = (blockIdx.x * blockDim.x + threadIdx.x) >> 6;
    const int nwaves = (gridDim.x * blockDim.x) >> 6;
    const int groups = (E_ + 15) >> 4;
    for (int g = wave; g < groups; g += nwaves) {
        const int bu = __builtin_amdgcn_readfirstlane(g << 4);
#pragma unroll 4
        for (int tt = 0; tt < 16; ++tt) {
            const int e = bu + tt;
            const float v = (e < E_) ? agg_out[(size_t)e * DD + lane] : 0.f;
            P[w][tt * 64 + (lane ^ ((tt & 7) << 3))] = f2bf(v);
        }
        const int row = lane & 15;
        const int d0  = (lane >> 4) * 8;
        const int sw  = (row & 7) << 3;
        const bf16x8 a0 = *reinterpret_cast<const bf16x8*>(&P[w][row * 64 + ((d0)      ^ sw)]);
        const bf16x8 a1 = *reinterpret_cast<const bf16x8*>(&P[w][row * 64 + ((d0 + 32) ^ sw)]);
        f32x4 acc0 = {0.f, 0.f, 0.f, 0.f}, acc1 = acc0, acc2 = acc0, acc3 = acc0;
        MFMA8(bw, a0, a1)
        const int rb4 = (lane >> 4) * 4;
        const int cl  = lane & 15;
#pragma unroll
        for (int r = 0; r < 4; ++r) {
            U[w][(rb4 + r) * MST + cl + 0]  = acc0[r];
            U[w][(rb4 + r) * MST + cl + 16] = acc1[r];
            U[w][(rb4 + r) * MST + cl + 32] = acc2[r];
            U[w][(rb4 + r) * MST + cl + 48] = acc3[r];
        }
#pragma unroll 4
        for (int tt = 0; tt < 16; ++tt) {
            const int e = bu + tt;
            if (e < E_) {
                const float x = feat[(size_t)e * DD + lane] + emb[rel[e] * DD + lane];
                agg_out[(size_t)e * DD + lane] = fmaxf(x + U[w][tt * MST + lane], 0.f);
            }
        }
    }
}

extern "C" void kernel_launch(void* const* d_in, const int* in_sizes, int n_in,
                              void* d_out, int out_size, void* d_ws, size_t ws_size,
                              hipStream_t stream) {
    const float* feat = (const float*)d_in[0];
    const float* emb  = (const float*)d_in[1];
    const float* Wmsg = (const float*)d_in[2];
    const float* Wupd = (const float*)d_in[3];
    const int*   rel  = (const int*)d_in[4];
    const int*   ab   = (const int*)d_in[5];
    const int*   bc   = (const int*)d_in[6];
    const int*   ac   = (const int*)d_in[7];

    const int E_ = in_sizes[0] / DD;
    const int T_ = in_sizes[5];

    const int    NBUK   = (E_ + (1 << BUK_BITS) - 1) >> BUK_BITS;      // <= 256
    const int    ntab   = NBUK * NBLK_P;
    const int    nblk_s = (ntab + SCAN_CH - 1) / SCAN_CH;
    const size_t xbytes = (size_t)E_ * DD * sizeof(unsigned short);    // 128 MB
    const size_t tbytes = (size_t)T_ * sizeof(u64);                    // 16 MB
    const size_t gbytes = ((size_t)ntab * sizeof(unsigned int) + 255u) & ~(size_t)255u;
    const size_t need   = 2 * xbytes + 2 * tbytes + 2 * gbytes + 4096 * sizeof(unsigned int);

    const bool fast = (E_ <= (1 << 20)) && ((E_ & 15) == 0) && (NBUK <= 256) &&
                      (nblk_s <= 1024) && (ws_size >= need);

    if (fast) {
        char* p = (char*)d_ws;
        unsigned short* xtab  = (unsigned short*)p;  p += xbytes;
        unsigned short* aggbf = (unsigned short*)p;  p += xbytes;
        u64*            tep   = (u64*)p;             p += tbytes;
        u64*            teps  = (u64*)p;             p += tbytes;
        unsigned int*   gtabC = (unsigned int*)p;    p += gbytes;
        unsigned int*   gtabO = (unsigned int*)p;    p += gbytes;
        unsigned int*   bsum  = (unsigned int*)p;

        const int chunk  = (T_ + NBLK_P - 1) / NBLK_P;
        const int nwaves = 2048 * 256 / 64;   // 8192 waves, fully resident at <=20KB LDS
        int S = (T_ + nwaves - 1) / nwaves;
        S = (S + 15) & ~15;

        hipMemsetAsync(aggbf, 0, xbytes, stream);
        hipLaunchKernelGGL(xprep_hist2_kernel, dim3(NBLK_P), dim3(256), 0, stream,
                           (const float4*)feat, (const float4*)emb, rel, xtab, E_ * 16,
                           ac, gtabC, T_, chunk, NBUK);
        hipLaunchKernelGGL(scanA_kernel, dim3(nblk_s), dim3(256), 0, stream, gtabC, bsum, ntab);
        hipLaunchKernelGGL(scanB_kernel, dim3(1), dim3(1024), 0, stream, bsum, nblk_s);
        hipLaunchKernelGGL(scanC_kernel, dim3(nblk_s), dim3(256), 0, stream,
                           gtabC, bsum, gtabO, ntab);
        hipLaunchKernelGGL(part_kernel, dim3(NBLK_P), dim3(256), 0, stream,
                           ab, bc, ac, gtabO, tep, T_, chunk, NBUK);
        hipLaunchKernelGGL(lsort_kernel, dim3(NBUK), dim3(256), 0, stream,
                           tep, gtabO, teps, T_, NBUK);
        hipLaunchKernelGGL(tri_csr5_kernel, dim3(2048), dim3(256), 0, stream,
                           xtab, Wmsg, teps, aggbf, T_, S);
        hipLaunchKernelGGL(upd_fast2, dim3(2048), dim3(256), 0, stream,
                           xtab, aggbf, Wupd, (float*)d_out, E_);
    } else {
        float* agg = (float*)d_out;
        hipMemsetAsync(d_out, 0, (size_t)E_ * DD * sizeof(float), stream);
        hipLaunchKernelGGL(tri_fb, dim3(2048), dim3(256), 0, stream,
                           feat, emb, Wmsg, rel, ab, bc, ac, agg, T_);
        hipLaunchKernelGGL(upd_fb, dim3(2048), dim3(256), 0, stream,
                           feat, emb, Wupd, rel, agg, E_);
    }
}

// Round 14
// 414.388 us; speedup vs baseline: 1.2035x; 1.2035x over previous
//
#include <hip/hip_runtime.h>
#include <hip/hip_bf16.h>

#define DD 64
#define SCAN_CH 1024
#define MST 68
#define NBLK_P 1024
#define BUK_BITS 12
#define TRI_BLOCKS 1536   // 6 blocks/CU x 256 CU: exact resident capacity at 25.6KB LDS

typedef __attribute__((ext_vector_type(8))) short bf16x8;
typedef __attribute__((ext_vector_type(4))) float f32x4;
typedef unsigned long long u64;

__device__ __forceinline__ unsigned short f2bf(float f) {
    unsigned int u = __float_as_uint(f);
    unsigned int r = (u + 0x7fffu + ((u >> 16) & 1u)) >> 16;   // RNE
    return (unsigned short)r;
}
__device__ __forceinline__ float bf2f(unsigned short u) {
    return __uint_as_float((unsigned int)u << 16);
}
__device__ __forceinline__ unsigned int pack2(float lo, float hi) {
    return (unsigned int)f2bf(lo) | ((unsigned int)f2bf(hi) << 16);
}
__device__ __forceinline__ unsigned int cvt_pk_bf16(float lo, float hi) {
    unsigned int r;
    asm("v_cvt_pk_bf16_f32 %0, %1, %2" : "=v"(r) : "v"(lo), "v"(hi));
    return r;
}
__device__ __forceinline__ unsigned int prod2(unsigned int a, unsigned int b) {
    const float la = __uint_as_float(a << 16);
    const float ha = __uint_as_float(a & 0xffff0000u);
    const float lb = __uint_as_float(b << 16);
    const float hb = __uint_as_float(b & 0xffff0000u);
    return cvt_pk_bf16(la * lb, ha * hb);
}
__device__ __forceinline__ void pk_atomic_add_bf16(unsigned short* addr, unsigned int data) {
    asm volatile("global_atomic_pk_add_bf16 %0, %1, off" :: "v"(addr), "v"(data) : "memory");
}

// B frag for 16x16x32: lane l holds B[k = ks*32 + (l>>4)*8 + b][col = nt*16 + (l&15)]
__device__ __forceinline__ void load_w_frags(const float* __restrict__ W, int lane,
                                             bf16x8 bw[4][2]) {
    const int kl = (lane >> 4) * 8;
    const int cl = lane & 15;
#pragma unroll
    for (int nt = 0; nt < 4; ++nt)
#pragma unroll
        for (int ks = 0; ks < 2; ++ks)
#pragma unroll
            for (int b = 0; b < 8; ++b)
                bw[nt][ks][b] = (short)f2bf(W[(ks * 32 + kl + b) * DD + nt * 16 + cl]);
}

#define MFMA8(BW, A0, A1)                                                        \
    acc0 = __builtin_amdgcn_mfma_f32_16x16x32_bf16(A0, BW[0][0], acc0, 0, 0, 0); \
    acc0 = __builtin_amdgcn_mfma_f32_16x16x32_bf16(A1, BW[0][1], acc0, 0, 0, 0); \
    acc1 = __builtin_amdgcn_mfma_f32_16x16x32_bf16(A0, BW[1][0], acc1, 0, 0, 0); \
    acc1 = __builtin_amdgcn_mfma_f32_16x16x32_bf16(A1, BW[1][1], acc1, 0, 0, 0); \
    acc2 = __builtin_amdgcn_mfma_f32_16x16x32_bf16(A0, BW[2][0], acc2, 0, 0, 0); \
    acc2 = __builtin_amdgcn_mfma_f32_16x16x32_bf16(A1, BW[2][1], acc2, 0, 0, 0); \
    acc3 = __builtin_amdgcn_mfma_f32_16x16x32_bf16(A0, BW[3][0], acc3, 0, 0, 0); \
    acc3 = __builtin_amdgcn_mfma_f32_16x16x32_bf16(A1, BW[3][1], acc3, 0, 0, 0);

// ---------- x-table prep (pure, as in round 12) ----------
__global__ __launch_bounds__(256) void xprep_kernel(
    const float4* __restrict__ feat4, const float4* __restrict__ emb4,
    const int* __restrict__ rel, unsigned short* __restrict__ xtab, int n4) {
    int i = blockIdx.x * blockDim.x + threadIdx.x;
    const int stride = gridDim.x * blockDim.x;
    for (; i < n4; i += stride) {
        const int e  = i >> 4;
        const int re = rel[e];
        const float4 f = feat4[i];
        const float4 g = emb4[re * 16 + (i & 15)];
        ushort4 o;
        o.x = f2bf(f.x + g.x); o.y = f2bf(f.y + g.y);
        o.z = f2bf(f.z + g.z); o.w = f2bf(f.w + g.w);
        *reinterpret_cast<ushort4*>(&xtab[(size_t)i * 4]) = o;
    }
}

// ---------- pass 1: per-block LDS-private coarse histogram (buk = ac>>12) ----------
__global__ __launch_bounds__(256) void histc_kernel(
    const int* __restrict__ ac, unsigned int* __restrict__ gtab,
    int T_, int chunk, int NBUK) {
    __shared__ unsigned int lc[256];
    const int b = blockIdx.x, tid = threadIdx.x;
    lc[tid] = 0;
    __syncthreads();
    const int lo = b * chunk, hi = min(lo + chunk, T_);
    for (int t = lo + tid; t < hi; t += 256) atomicAdd(&lc[ac[t] >> BUK_BITS], 1u);
    __syncthreads();
    for (int i = tid; i < NBUK; i += 256) gtab[i * NBLK_P + b] = lc[i];
}

// ---------- scan over gtab ----------
__global__ __launch_bounds__(256) void scanA_kernel(const unsigned int* __restrict__ cnt,
                                                    unsigned int* __restrict__ bsum, int n) {
    __shared__ unsigned int s[256];
    const int b = blockIdx.x, tid = threadIdx.x;
    const int base = b * SCAN_CH + tid * 4;
    unsigned int v = 0;
#pragma unroll
    for (int k = 0; k < 4; ++k) { const int i = base + k; if (i < n) v += cnt[i]; }
    s[tid] = v; __syncthreads();
    for (int off = 128; off > 0; off >>= 1) {
        if (tid < off) s[tid] += s[tid + off];
        __syncthreads();
    }
    if (tid == 0) bsum[b] = s[0];
}

__global__ __launch_bounds__(1024) void scanB_kernel(unsigned int* bsum, int nb) {
    __shared__ unsigned int s[1024];
    const int tid = threadIdx.x;
    s[tid] = (tid < nb) ? bsum[tid] : 0u;
    __syncthreads();
    for (int off = 1; off < 1024; off <<= 1) {
        const unsigned int t = (tid >= off) ? s[tid - off] : 0u;
        __syncthreads();
        s[tid] += t;
        __syncthreads();
    }
    if (tid < nb) bsum[tid] = (tid == 0) ? 0u : s[tid - 1];   // exclusive
}

__global__ __launch_bounds__(256) void scanC_kernel(const unsigned int* __restrict__ cnt,
                                                    const unsigned int* __restrict__ bsum,
                                                    unsigned int* __restrict__ offs, int n) {
    __shared__ unsigned int s[256];
    const int b = blockIdx.x, tid = threadIdx.x;
    const int base = b * SCAN_CH + tid * 4;
    unsigned int v[4], sum = 0;
#pragma unroll
    for (int k = 0; k < 4; ++k) { const int i = base + k; v[k] = (i < n) ? cnt[i] : 0u; sum += v[k]; }
    s[tid] = sum; __syncthreads();
    for (int off = 1; off < 256; off <<= 1) {
        const unsigned int t = (tid >= off) ? s[tid - off] : 0u;
        __syncthreads();
        s[tid] += t;
        __syncthreads();
    }
    unsigned int run = bsum[b] + (s[tid] - sum);
#pragma unroll
    for (int k = 0; k < 4; ++k) { const int i = base + k; if (i < n) offs[i] = run; run += v[k]; }
}

// ---------- pass 2: partition into buckets, packed 8B ----------
__global__ __launch_bounds__(256) void part_kernel(
    const int* __restrict__ ab, const int* __restrict__ bc, const int* __restrict__ ac,
    const unsigned int* __restrict__ gtabO, u64* __restrict__ tep,
    int T_, int chunk, int NBUK) {
    __shared__ unsigned int cur[256];
    const int b = blockIdx.x, tid = threadIdx.x;
    for (int i = tid; i < NBUK; i += 256) cur[i] = gtabO[i * NBLK_P + b];
    __syncthreads();
    const int lo = b * chunk, hi = min(lo + chunk, T_);
    for (int t = lo + tid; t < hi; t += 256) {
        const int e = ac[t];
        const unsigned int pos = atomicAdd(&cur[e >> BUK_BITS], 1u);
        tep[pos] = (u64)(unsigned)ab[t] | ((u64)(unsigned)bc[t] << 20) | ((u64)(unsigned)e << 40);
    }
}

// ---------- pass 3: per-bucket LDS counting sort + targeted aggbf zero-fill ----------
// Zero-fills rows that will only receive ATOMIC contributions in tri_csr4:
// deg==0 edges, and edges whose sorted range [lo,hi) touches a wave boundary
// (multiple of S, or end T). Replaces the 128MB aggbf memset (~21us) with ~18MB.
__global__ __launch_bounds__(256) void lsort_kernel(
    const u64* __restrict__ tep, const unsigned int* __restrict__ gtabO,
    u64* __restrict__ teps, unsigned short* __restrict__ aggbf,
    int T_, int NBUK, int E_, int S) {
    __shared__ unsigned int cnt4[1 << BUK_BITS];   // 16 KB (starts, then ends)
    __shared__ unsigned int st4[1 << BUK_BITS];    // 16 KB (saved starts)
    __shared__ unsigned int part[256];
    const int buk = blockIdx.x, tid = threadIdx.x;
    const int s0 = (int)gtabO[buk * NBLK_P];
    const int s1 = (buk + 1 < NBUK) ? (int)gtabO[(buk + 1) * NBLK_P] : T_;
    const int n  = s1 - s0;

    for (int i = tid; i < (1 << BUK_BITS); i += 256) cnt4[i] = 0;
    __syncthreads();
    for (int i = tid; i < n; i += 256) {
        const int elo = (int)((tep[s0 + i] >> 40) & ((1u << BUK_BITS) - 1));
        atomicAdd(&cnt4[elo], 1u);
    }
    __syncthreads();
    unsigned int s = 0;
#pragma unroll
    for (int k = 0; k < 16; ++k) s += cnt4[tid * 16 + k];
    part[tid] = s;
    __syncthreads();
    for (int off = 1; off < 256; off <<= 1) {
        const unsigned int t = (tid >= off) ? part[tid - off] : 0u;
        __syncthreads();
        part[tid] += t;
        __syncthreads();
    }
    unsigned int run = (tid ? part[tid - 1] : 0u);
#pragma unroll
    for (int k = 0; k < 16; ++k) {
        const unsigned int c = cnt4[tid * 16 + k];
        cnt4[tid * 16 + k] = run;
        st4[tid * 16 + k]  = run;
        run += c;
    }
    __syncthreads();
    for (int i = tid; i < n; i += 256) {
        const u64 v  = tep[s0 + i];
        const int elo = (int)((v >> 40) & ((1u << BUK_BITS) - 1));
        const unsigned int pos = atomicAdd(&cnt4[elo], 1u);
        teps[s0 + pos] = v;
    }
    __syncthreads();

    // targeted zero-fill
    const int ebase = buk << BUK_BITS;
    for (int i = tid; i < (1 << BUK_BITS); i += 256) {
        const int e = ebase + i;
        if (e >= E_) break;
        const int lo  = s0 + (int)st4[i];
        const int hi  = s0 + (int)cnt4[i];     // cnt4 now holds ends
        const int deg = hi - lo;
        const int fl  = (lo == 0) ? -1 : (lo - 1) / S;
        const bool needZero = (deg == 0) || (hi >= T_) || (hi / S > fl);
        if (needZero) {
            const uint4 z = make_uint4(0u, 0u, 0u, 0u);
            unsigned short* row = &aggbf[(size_t)e * DD];
#pragma unroll
            for (int j = 0; j < 8; ++j)
                *reinterpret_cast<uint4*>(&row[j * 8]) = z;
        }
    }
}

// ---------- fused CSR message+reduce (round-12 hot loop; exact-fit grid) ----------
__global__ __launch_bounds__(256) void tri_csr4_kernel(
    const unsigned short* __restrict__ xtab, const float* __restrict__ Wmsg,
    const u64* __restrict__ tep, unsigned short* __restrict__ aggbf,
    int T_, int S) {
    __shared__ unsigned short P[4][16 * 64];
    __shared__ float M[4][16 * MST];

    const int lane = threadIdx.x & 63;
    const int w    = threadIdx.x >> 6;

    bf16x8 bw[4][2];
    load_w_frags(Wmsg, lane, bw);

    const int gw = (blockIdx.x * blockDim.x + threadIdx.x) >> 6;
    const int p0 = gw * S;
    if (p0 >= T_) return;
    const int p1 = min(p0 + S, T_);

    const int rh = lane >> 3;
    const int cb = (lane & 7) * 8;

    int cur_e = -1; float sum = 0.f;
    int e_sv  = -1; float sum_sv = 0.f;
    bool have_sv = false;

    for (int t0 = p0; t0 < p1; t0 += 16) {
        const int cnt = min(16, p1 - t0);
        const u64 tq = tep[t0 + min(lane & 15, cnt - 1)];
        const int pa = (int)(tq & 0xFFFFFu);
        const int pb = (int)((tq >> 20) & 0xFFFFFu);
        const int pe = (int)(tq >> 40);

#pragma unroll
        for (int half = 0; half < 2; ++half) {
            const int ttl = half * 8 + rh;
            const int eA  = __shfl(pa, ttl, 64);
            const int eB  = __shfl(pb, ttl, 64);
            const uint4 va = *reinterpret_cast<const uint4*>(&xtab[(size_t)eA * DD + cb]);
            const uint4 vb = *reinterpret_cast<const uint4*>(&xtab[(size_t)eB * DD + cb]);
            uint4 pk;
            pk.x = prod2(va.x, vb.x);
            pk.y = prod2(va.y, vb.y);
            pk.z = prod2(va.z, vb.z);
            pk.w = prod2(va.w, vb.w);
            const int swz = (ttl & 7) << 3;
            *reinterpret_cast<uint4*>(&P[w][ttl * 64 + (cb ^ swz)]) = pk;
        }

        const int row = lane & 15;
        const int d0  = (lane >> 4) * 8;
        const int sw  = (row & 7) << 3;
        const bf16x8 a0 = *reinterpret_cast<const bf16x8*>(&P[w][row * 64 + ((d0)      ^ sw)]);
        const bf16x8 a1 = *reinterpret_cast<const bf16x8*>(&P[w][row * 64 + ((d0 + 32) ^ sw)]);

        f32x4 acc0 = {0.f, 0.f, 0.f, 0.f}, acc1 = acc0, acc2 = acc0, acc3 = acc0;
        MFMA8(bw, a0, a1)

        const int rb4 = (lane >> 4) * 4;
        const int cl  = lane & 15;
#pragma unroll
        for (int r = 0; r < 4; ++r) {
            M[w][(rb4 + r) * MST + cl + 0]  = fmaxf(acc0[r], 0.f);
            M[w][(rb4 + r) * MST + cl + 16] = fmaxf(acc1[r], 0.f);
            M[w][(rb4 + r) * MST + cl + 32] = fmaxf(acc2[r], 0.f);
            M[w][(rb4 + r) * MST + cl + 48] = fmaxf(acc3[r], 0.f);
        }

        for (int r = 0; r < cnt; ++r) {
            const int e_r = __builtin_amdgcn_readlane(pe, r);
            if (e_r != cur_e) {
                if (cur_e >= 0) {
                    if (!have_sv) { e_sv = cur_e; sum_sv = sum; have_sv = true; }
                    else aggbf[(size_t)cur_e * DD + lane] = f2bf(sum);  // exclusive owner
                }
                cur_e = e_r; sum = 0.f;
            }
            sum += M[w][r * MST + lane];
        }
    }

    // boundary edges -> pk-atomics onto rows pre-zeroed by lsort
    {
        const float nsum = __shfl_xor(sum, 1, 64);
        if (cur_e >= 0 && !(lane & 1))
            pk_atomic_add_bf16(&aggbf[(size_t)cur_e * DD + lane], pack2(sum, nsum));
        if (have_sv) {
            const float nsv = __shfl_xor(sum_sv, 1, 64);
            if (!(lane & 1))
                pk_atomic_add_bf16(&aggbf[(size_t)e_sv * DD + lane], pack2(sum_sv, nsv));
        }
    }
}

// ---------- update pass (round-12 version) ----------
__global__ __launch_bounds__(256) void upd_fast(
    const unsigned short* __restrict__ xtab, const unsigned short* __restrict__ aggbf,
    const float* __restrict__ Wupd, float* __restrict__ out, int E_) {
    __shared__ unsigned short P[4][16 * 64];
    __shared__ float U[4][16 * MST];

    const int lane = threadIdx.x & 63;
    const int w    = threadIdx.x >> 6;

    bf16x8 bw[4][2];
    load_w_frags(Wupd, lane, bw);

    const int wave   = (blockIdx.x * blockDim.x + threadIdx.x) >> 6;
    const int nwaves = (gridDim.x * blockDim.x) >> 6;
    const int groups = E_ >> 4;

    for (int g = wave; g < groups; g += nwaves) {
        const int bu = g << 4;

#pragma unroll
        for (int half = 0; half < 2; ++half) {
            const int flat = half * 512 + lane * 8;
            const int row  = flat >> 6;
            const int colb = flat & 63;
            const uint4 v = *reinterpret_cast<const uint4*>(&aggbf[(size_t)bu * DD + flat]);
            *reinterpret_cast<uint4*>(&P[w][row * 64 + (colb ^ ((row & 7) << 3))]) = v;
        }

        const int row = lane & 15;
        const int d0  = (lane >> 4) * 8;
        const int sw  = (row & 7) << 3;
        const bf16x8 a0 = *reinterpret_cast<const bf16x8*>(&P[w][row * 64 + ((d0)      ^ sw)]);
        const bf16x8 a1 = *reinterpret_cast<const bf16x8*>(&P[w][row * 64 + ((d0 + 32) ^ sw)]);

        f32x4 acc0 = {0.f, 0.f, 0.f, 0.f}, acc1 = acc0, acc2 = acc0, acc3 = acc0;
        MFMA8(bw, a0, a1)

        const int rb4 = (lane >> 4) * 4;
        const int cl  = lane & 15;
#pragma unroll
        for (int r = 0; r < 4; ++r) {
            U[w][(rb4 + r) * MST + cl + 0]  = acc0[r];
            U[w][(rb4 + r) * MST + cl + 16] = acc1[r];
            U[w][(rb4 + r) * MST + cl + 32] = acc2[r];
            U[w][(rb4 + r) * MST + cl + 48] = acc3[r];
        }

#pragma unroll
        for (int tt = 0; tt < 16; ++tt) {
            const int e   = bu + tt;
            const float x = bf2f(xtab[(size_t)e * DD + lane]);
            out[(size_t)e * DD + lane] = fmaxf(x + U[w][tt * MST + lane], 0.f);
        }
    }
}

// ---------- tier 1: fully general fallback ----------
__global__ __launch_bounds__(256) void tri_fb(
    const float* __restrict__ feat, const float* __restrict__ emb,
    const float* __restrict__ Wmsg, const int* __restrict__ rel,
    const int* __restrict__ ab, const int* __restrict__ bc,
    const int* __restrict__ ac, float* __restrict__ agg, int T_) {
    __shared__ unsigned short P[4][16 * 64];
    const int lane = threadIdx.x & 63;
    const int w    = threadIdx.x >> 6;
    bf16x8 bw[4][2];
    load_w_frags(Wmsg, lane, bw);
    const int wave   = (blockIdx.x * blockDim.x + threadIdx.x) >> 6;
    const int nwaves = (gridDim.x * blockDim.x) >> 6;
    const int groups = (T_ + 15) >> 4;
    for (int g = wave; g < groups; g += nwaves) {
        const int bu = __builtin_amdgcn_readfirstlane(g << 4);
#pragma unroll 4
        for (int tt = 0; tt < 16; ++tt) {
            const int t = bu + tt;
            float p = 0.f;
            if (t < T_) {
                const int ea = ab[t], eb = bc[t];
                const float xa = feat[ea * DD + lane] + emb[rel[ea] * DD + lane];
                const float xb = feat[eb * DD + lane] + emb[rel[eb] * DD + lane];
                p = xa * xb;
            }
            P[w][tt * 64 + (lane ^ ((tt & 7) << 3))] = f2bf(p);
        }
        const int row = lane & 15;
        const int d0  = (lane >> 4) * 8;
        const int sw  = (row & 7) << 3;
        const bf16x8 a0 = *reinterpret_cast<const bf16x8*>(&P[w][row * 64 + ((d0)      ^ sw)]);
        const bf16x8 a1 = *reinterpret_cast<const bf16x8*>(&P[w][row * 64 + ((d0 + 32) ^ sw)]);
        f32x4 acc0 = {0.f, 0.f, 0.f, 0.f}, acc1 = acc0, acc2 = acc0, acc3 = acc0;
        MFMA8(bw, a0, a1)
        const int rb4 = (lane >> 4) * 4;
        const int cl  = lane & 15;
#pragma unroll
        for (int r = 0; r < 4; ++r) {
            const int t = bu + rb4 + r;
            if (t < T_) {
                float* dst = &agg[(size_t)ac[t] * DD + cl];
                atomicAdd(dst + 0,  fmaxf(acc0[r], 0.f));
                atomicAdd(dst + 16, fmaxf(acc1[r], 0.f));
                atomicAdd(dst + 32, fmaxf(acc2[r], 0.f));
                atomicAdd(dst + 48, fmaxf(acc3[r], 0.f));
            }
        }
    }
}

__global__ __launch_bounds__(256) void upd_fb(
    const float* __restrict__ feat, const float* __restrict__ emb,
    const float* __restrict__ Wupd, const int* __restrict__ rel,
    float* __restrict__ agg_out, int E_) {
    __shared__ unsigned short P[4][16 * 64];
    __shared__ float U[4][16 * MST];
    const int lane = threadIdx.x & 63;
    const int w    = threadIdx.x >> 6;
    bf16x8 bw[4][2];
    load_w_frags(Wupd, lane, bw);
    const int wave   = (blockIdx.x * blockDim.x + threadIdx.x) >> 6;
    const int nwaves = (gridDim.x * blockDim.x) >> 6;
    const int groups = (E_ + 15) >> 4;
    for (int g = wave; g < groups; g += nwaves) {
        const int bu = __builtin_amdgcn_readfirstlane(g << 4);
#pragma unroll 4
        for (int tt = 0; tt < 16; ++tt) {
            const int e = bu + tt;
            const float v = (e < E_) ? agg_out[(size_t)e * DD + lane] : 0.f;
            P[w][tt * 64 + (lane ^ ((tt & 7) << 3))] = f2bf(v);
        }
        const int row = lane & 15;
        const int d0  = (lane >> 4) * 8;
        const int sw  = (row & 7) << 3;
        const bf16x8 a0 = *reinterpret_cast<const bf16x8*>(&P[w][row * 64 + ((d0)      ^ sw)]);
        const bf16x8 a1 = *reinterpret_cast<const bf16x8*>(&P[w][row * 64 + ((d0 + 32) ^ sw)]);
        f32x4 acc0 = {0.f, 0.f, 0.f, 0.f}, acc1 = acc0, acc2 = acc0, acc3 = acc0;
        MFMA8(bw, a0, a1)
        const int rb4 = (lane >> 4) * 4;
        const int cl  = lane & 15;
#pragma unroll
        for (int r = 0; r < 4; ++r) {
            U[w][(rb4 + r) * MST + cl + 0]  = acc0[r];
            U[w][(rb4 + r) * MST + cl + 16] = acc1[r];
            U[w][(rb4 + r) * MST + cl + 32] = acc2[r];
            U[w][(rb4 + r) * MST + cl + 48] = acc3[r];
        }
#pragma unroll 4
        for (int tt = 0; tt < 16; ++tt) {
            const int e = bu + tt;
            if (e < E_) {
                const float x = feat[(size_t)e * DD + lane] + emb[rel[e] * DD + lane];
                agg_out[(size_t)e * DD + lane] = fmaxf(x + U[w][tt * MST + lane], 0.f);
            }
        }
    }
}

extern "C" void kernel_launch(void* const* d_in, const int* in_sizes, int n_in,
                              void* d_out, int out_size, void* d_ws, size_t ws_size,
                              hipStream_t stream) {
    const float* feat = (const float*)d_in[0];
    const float* emb  = (const float*)d_in[1];
    const float* Wmsg = (const float*)d_in[2];
    const float* Wupd = (const float*)d_in[3];
    const int*   rel  = (const int*)d_in[4];
    const int*   ab   = (const int*)d_in[5];
    const int*   bc   = (const int*)d_in[6];
    const int*   ac   = (const int*)d_in[7];

    const int E_ = in_sizes[0] / DD;
    const int T_ = in_sizes[5];

    const int    NBUK   = (E_ + (1 << BUK_BITS) - 1) >> BUK_BITS;      // <= 256
    const int    ntab   = NBUK * NBLK_P;
    const int    nblk_s = (ntab + SCAN_CH - 1) / SCAN_CH;
    const size_t xbytes = (size_t)E_ * DD * sizeof(unsigned short);    // 128 MB
    const size_t tbytes = (size_t)T_ * sizeof(u64);                    // 16 MB
    const size_t gbytes = ((size_t)ntab * sizeof(unsigned int) + 255u) & ~(size_t)255u;
    const size_t need   = 2 * xbytes + 2 * tbytes + 2 * gbytes + 4096 * sizeof(unsigned int);

    const bool fast = (E_ <= (1 << 20)) && ((E_ & 15) == 0) && (NBUK <= 256) &&
                      (nblk_s <= 1024) && (ws_size >= need);

    if (fast) {
        char* p = (char*)d_ws;
        unsigned short* xtab  = (unsigned short*)p;  p += xbytes;
        unsigned short* aggbf = (unsigned short*)p;  p += xbytes;
        u64*            tep   = (u64*)p;             p += tbytes;
        u64*            teps  = (u64*)p;             p += tbytes;
        unsigned int*   gtabC = (unsigned int*)p;    p += gbytes;
        unsigned int*   gtabO = (unsigned int*)p;    p += gbytes;
        unsigned int*   bsum  = (unsigned int*)p;

        const int chunk  = (T_ + NBLK_P - 1) / NBLK_P;
        const int nwaves = TRI_BLOCKS * 256 / 64;    // 6144 waves, exact-fit (no tail)
        int S = (T_ + nwaves - 1) / nwaves;
        S = (S + 15) & ~15;

        hipLaunchKernelGGL(xprep_kernel, dim3(2048), dim3(256), 0, stream,
                           (const float4*)feat, (const float4*)emb, rel, xtab, E_ * 16);
        hipLaunchKernelGGL(histc_kernel, dim3(NBLK_P), dim3(256), 0, stream,
                           ac, gtabC, T_, chunk, NBUK);
        hipLaunchKernelGGL(scanA_kernel, dim3(nblk_s), dim3(256), 0, stream, gtabC, bsum, ntab);
        hipLaunchKernelGGL(scanB_kernel, dim3(1), dim3(1024), 0, stream, bsum, nblk_s);
        hipLaunchKernelGGL(scanC_kernel, dim3(nblk_s), dim3(256), 0, stream,
                           gtabC, bsum, gtabO, ntab);
        hipLaunchKernelGGL(part_kernel, dim3(NBLK_P), dim3(256), 0, stream,
                           ab, bc, ac, gtabO, tep, T_, chunk, NBUK);
        hipLaunchKernelGGL(lsort_kernel, dim3(NBUK), dim3(256), 0, stream,
                           tep, gtabO, teps, aggbf, T_, NBUK, E_, S);
        hipLaunchKernelGGL(tri_csr4_kernel, dim3(TRI_BLOCKS), dim3(256), 0, stream,
                           xtab, Wmsg, teps, aggbf, T_, S);
        hipLaunchKernelGGL(upd_fast, dim3(2048), dim3(256), 0, stream,
                           xtab, aggbf, Wupd, (float*)d_out, E_);
    } else {
        float* agg = (float*)d_out;
        hipMemsetAsync(d_out, 0, (size_t)E_ * DD * sizeof(float), stream);
        hipLaunchKernelGGL(tri_fb, dim3(2048), dim3(256), 0, stream,
                           feat, emb, Wmsg, rel, ab, bc, ac, agg, T_);
        hipLaunchKernelGGL(upd_fb, dim3(2048), dim3(256), 0, stream,
                           feat, emb, Wupd, rel, agg, E_);
    }
}

// Round 15
// 375.539 us; speedup vs baseline: 1.3280x; 1.1034x over previous
//
#include <hip/hip_runtime.h>
#include <hip/hip_bf16.h>

#define DD 64
#define SCAN_CH 1024
#define MST 68
#define NBLK_P 1024
#define BUK_BITS 12

typedef __attribute__((ext_vector_type(8))) short bf16x8;
typedef __attribute__((ext_vector_type(4))) float f32x4;
typedef unsigned long long u64;

__device__ __forceinline__ unsigned short f2bf(float f) {
    unsigned int u = __float_as_uint(f);
    unsigned int r = (u + 0x7fffu + ((u >> 16) & 1u)) >> 16;   // RNE
    return (unsigned short)r;
}
__device__ __forceinline__ float bf2f(unsigned short u) {
    return __uint_as_float((unsigned int)u << 16);
}
__device__ __forceinline__ unsigned int pack2(float lo, float hi) {
    return (unsigned int)f2bf(lo) | ((unsigned int)f2bf(hi) << 16);
}
__device__ __forceinline__ unsigned int cvt_pk_bf16(float lo, float hi) {
    unsigned int r;
    asm("v_cvt_pk_bf16_f32 %0, %1, %2" : "=v"(r) : "v"(lo), "v"(hi));
    return r;
}
__device__ __forceinline__ unsigned int prod2(unsigned int a, unsigned int b) {
    const float la = __uint_as_float(a << 16);
    const float ha = __uint_as_float(a & 0xffff0000u);
    const float lb = __uint_as_float(b << 16);
    const float hb = __uint_as_float(b & 0xffff0000u);
    return cvt_pk_bf16(la * lb, ha * hb);
}
__device__ __forceinline__ void pk_atomic_add_bf16(unsigned short* addr, unsigned int data) {
    asm volatile("global_atomic_pk_add_bf16 %0, %1, off" :: "v"(addr), "v"(data) : "memory");
}

// B frag for 16x16x32: lane l holds B[k = ks*32 + (l>>4)*8 + b][col = nt*16 + (l&15)]
__device__ __forceinline__ void load_w_frags(const float* __restrict__ W, int lane,
                                             bf16x8 bw[4][2]) {
    const int kl = (lane >> 4) * 8;
    const int cl = lane & 15;
#pragma unroll
    for (int nt = 0; nt < 4; ++nt)
#pragma unroll
        for (int ks = 0; ks < 2; ++ks)
#pragma unroll
            for (int b = 0; b < 8; ++b)
                bw[nt][ks][b] = (short)f2bf(W[(ks * 32 + kl + b) * DD + nt * 16 + cl]);
}

#define MFMA8(BW, A0, A1)                                                        \
    acc0 = __builtin_amdgcn_mfma_f32_16x16x32_bf16(A0, BW[0][0], acc0, 0, 0, 0); \
    acc0 = __builtin_amdgcn_mfma_f32_16x16x32_bf16(A1, BW[0][1], acc0, 0, 0, 0); \
    acc1 = __builtin_amdgcn_mfma_f32_16x16x32_bf16(A0, BW[1][0], acc1, 0, 0, 0); \
    acc1 = __builtin_amdgcn_mfma_f32_16x16x32_bf16(A1, BW[1][1], acc1, 0, 0, 0); \
    acc2 = __builtin_amdgcn_mfma_f32_16x16x32_bf16(A0, BW[2][0], acc2, 0, 0, 0); \
    acc2 = __builtin_amdgcn_mfma_f32_16x16x32_bf16(A1, BW[2][1], acc2, 0, 0, 0); \
    acc3 = __builtin_amdgcn_mfma_f32_16x16x32_bf16(A0, BW[3][0], acc3, 0, 0, 0); \
    acc3 = __builtin_amdgcn_mfma_f32_16x16x32_bf16(A1, BW[3][1], acc3, 0, 0, 0);

// ---------- x-table prep ----------
__global__ __launch_bounds__(256) void xprep_kernel(
    const float4* __restrict__ feat4, const float4* __restrict__ emb4,
    const int* __restrict__ rel, unsigned short* __restrict__ xtab, int n4) {
    int i = blockIdx.x * blockDim.x + threadIdx.x;
    const int stride = gridDim.x * blockDim.x;
    for (; i < n4; i += stride) {
        const int e  = i >> 4;
        const int re = rel[e];
        const float4 f = feat4[i];
        const float4 g = emb4[re * 16 + (i & 15)];
        ushort4 o;
        o.x = f2bf(f.x + g.x); o.y = f2bf(f.y + g.y);
        o.z = f2bf(f.z + g.z); o.w = f2bf(f.w + g.w);
        *reinterpret_cast<ushort4*>(&xtab[(size_t)i * 4]) = o;
    }
}

// ---------- pass 1: per-block LDS-private coarse histogram ----------
__global__ __launch_bounds__(256) void histc_kernel(
    const int* __restrict__ ac, unsigned int* __restrict__ gtab,
    int T_, int chunk, int NBUK) {
    __shared__ unsigned int lc[256];
    const int b = blockIdx.x, tid = threadIdx.x;
    lc[tid] = 0;
    __syncthreads();
    const int lo = b * chunk, hi = min(lo + chunk, T_);
    for (int t = lo + tid; t < hi; t += 256) atomicAdd(&lc[ac[t] >> BUK_BITS], 1u);
    __syncthreads();
    for (int i = tid; i < NBUK; i += 256) gtab[i * NBLK_P + b] = lc[i];
}

// ---------- scan over gtab ----------
__global__ __launch_bounds__(256) void scanA_kernel(const unsigned int* __restrict__ cnt,
                                                    unsigned int* __restrict__ bsum, int n) {
    __shared__ unsigned int s[256];
    const int b = blockIdx.x, tid = threadIdx.x;
    const int base = b * SCAN_CH + tid * 4;
    unsigned int v = 0;
#pragma unroll
    for (int k = 0; k < 4; ++k) { const int i = base + k; if (i < n) v += cnt[i]; }
    s[tid] = v; __syncthreads();
    for (int off = 128; off > 0; off >>= 1) {
        if (tid < off) s[tid] += s[tid + off];
        __syncthreads();
    }
    if (tid == 0) bsum[b] = s[0];
}

__global__ __launch_bounds__(1024) void scanB_kernel(unsigned int* bsum, int nb) {
    __shared__ unsigned int s[1024];
    const int tid = threadIdx.x;
    s[tid] = (tid < nb) ? bsum[tid] : 0u;
    __syncthreads();
    for (int off = 1; off < 1024; off <<= 1) {
        const unsigned int t = (tid >= off) ? s[tid - off] : 0u;
        __syncthreads();
        s[tid] += t;
        __syncthreads();
    }
    if (tid < nb) bsum[tid] = (tid == 0) ? 0u : s[tid - 1];   // exclusive
}

__global__ __launch_bounds__(256) void scanC_kernel(const unsigned int* __restrict__ cnt,
                                                    const unsigned int* __restrict__ bsum,
                                                    unsigned int* __restrict__ offs, int n) {
    __shared__ unsigned int s[256];
    const int b = blockIdx.x, tid = threadIdx.x;
    const int base = b * SCAN_CH + tid * 4;
    unsigned int v[4], sum = 0;
#pragma unroll
    for (int k = 0; k < 4; ++k) { const int i = base + k; v[k] = (i < n) ? cnt[i] : 0u; sum += v[k]; }
    s[tid] = sum; __syncthreads();
    for (int off = 1; off < 256; off <<= 1) {
        const unsigned int t = (tid >= off) ? s[tid - off] : 0u;
        __syncthreads();
        s[tid] += t;
        __syncthreads();
    }
    unsigned int run = bsum[b] + (s[tid] - sum);
#pragma unroll
    for (int k = 0; k < 4; ++k) { const int i = base + k; if (i < n) offs[i] = run; run += v[k]; }
}

// ---------- pass 2: partition into buckets, packed 8B ----------
__global__ __launch_bounds__(256) void part_kernel(
    const int* __restrict__ ab, const int* __restrict__ bc, const int* __restrict__ ac,
    const unsigned int* __restrict__ gtabO, u64* __restrict__ tep,
    int T_, int chunk, int NBUK) {
    __shared__ unsigned int cur[256];
    const int b = blockIdx.x, tid = threadIdx.x;
    for (int i = tid; i < NBUK; i += 256) cur[i] = gtabO[i * NBLK_P + b];
    __syncthreads();
    const int lo = b * chunk, hi = min(lo + chunk, T_);
    for (int t = lo + tid; t < hi; t += 256) {
        const int e = ac[t];
        const unsigned int pos = atomicAdd(&cur[e >> BUK_BITS], 1u);
        tep[pos] = (u64)(unsigned)ab[t] | ((u64)(unsigned)bc[t] << 20) | ((u64)(unsigned)e << 40);
    }
}

// ---------- pass 3: per-bucket LDS counting sort + targeted aggbf zero-fill ----------
__global__ __launch_bounds__(256) void lsort_kernel(
    const u64* __restrict__ tep, const unsigned int* __restrict__ gtabO,
    u64* __restrict__ teps, unsigned short* __restrict__ aggbf,
    int T_, int NBUK, int E_, int S) {
    __shared__ unsigned int cnt4[1 << BUK_BITS];   // starts -> ends
    __shared__ unsigned int st4[1 << BUK_BITS];    // saved starts
    __shared__ unsigned int part[256];
    const int buk = blockIdx.x, tid = threadIdx.x;
    const int s0 = (int)gtabO[buk * NBLK_P];
    const int s1 = (buk + 1 < NBUK) ? (int)gtabO[(buk + 1) * NBLK_P] : T_;
    const int n  = s1 - s0;

    for (int i = tid; i < (1 << BUK_BITS); i += 256) cnt4[i] = 0;
    __syncthreads();
    for (int i = tid; i < n; i += 256) {
        const int elo = (int)((tep[s0 + i] >> 40) & ((1u << BUK_BITS) - 1));
        atomicAdd(&cnt4[elo], 1u);
    }
    __syncthreads();
    unsigned int s = 0;
#pragma unroll
    for (int k = 0; k < 16; ++k) s += cnt4[tid * 16 + k];
    part[tid] = s;
    __syncthreads();
    for (int off = 1; off < 256; off <<= 1) {
        const unsigned int t = (tid >= off) ? part[tid - off] : 0u;
        __syncthreads();
        part[tid] += t;
        __syncthreads();
    }
    unsigned int run = (tid ? part[tid - 1] : 0u);
#pragma unroll
    for (int k = 0; k < 16; ++k) {
        const unsigned int c = cnt4[tid * 16 + k];
        cnt4[tid * 16 + k] = run;
        st4[tid * 16 + k]  = run;
        run += c;
    }
    __syncthreads();
    for (int i = tid; i < n; i += 256) {
        const u64 v  = tep[s0 + i];
        const int elo = (int)((v >> 40) & ((1u << BUK_BITS) - 1));
        const unsigned int pos = atomicAdd(&cnt4[elo], 1u);
        teps[s0 + pos] = v;
    }
    __syncthreads();

    // targeted zero-fill: rows that receive only atomic contributions
    const int ebase = buk << BUK_BITS;
    for (int i = tid; i < (1 << BUK_BITS); i += 256) {
        const int e = ebase + i;
        if (e >= E_) break;
        const int lo  = s0 + (int)st4[i];
        const int hi  = s0 + (int)cnt4[i];
        const int deg = hi - lo;
        const int fl  = (lo == 0) ? -1 : (lo - 1) / S;
        const bool needZero = (deg == 0) || (hi >= T_) || (hi / S > fl);
        if (needZero) {
            const uint4 z = make_uint4(0u, 0u, 0u, 0u);
            unsigned short* row = &aggbf[(size_t)e * DD];
#pragma unroll
            for (int j = 0; j < 8; ++j)
                *reinterpret_cast<uint4*>(&row[j * 8]) = z;
        }
    }
}

// ---------- fused CSR message+reduce, SOFTWARE-PIPELINED gathers ----------
// Per tile: issue tq(i+1) load at top (hides under prod2+MFMA); issue xtab
// gathers for tile i+1 before the serial reduce (gather latency hides under
// reduce + next prod2). Grid 2048 / S=256 (round-12 proven residency config).
__global__ __launch_bounds__(256) void tri_csr6_kernel(
    const unsigned short* __restrict__ xtab, const float* __restrict__ Wmsg,
    const u64* __restrict__ tep, unsigned short* __restrict__ aggbf,
    int T_, int S) {
    __shared__ unsigned short P[4][16 * 64];
    __shared__ float M[4][16 * MST];

    const int lane = threadIdx.x & 63;
    const int w    = threadIdx.x >> 6;

    bf16x8 bw[4][2];
    load_w_frags(Wmsg, lane, bw);

    const int gw = (blockIdx.x * blockDim.x + threadIdx.x) >> 6;
    const int p0 = gw * S;
    if (p0 >= T_) return;
    const int p1 = min(p0 + S, T_);

    const int rh = lane >> 3;          // row within half (0..7)
    const int cb = (lane & 7) * 8;     // 8-elem chunk within row

    int cur_e = -1; float sum = 0.f;
    int e_sv  = -1; float sum_sv = 0.f;
    bool have_sv = false;

    // ---- prologue: tile-0 indices + gathers ----
    u64 tq = tep[p0 + min(lane & 15, (p1 - p0) - 1)];
    uint4 vA0, vB0, vA1, vB1;
    {
        const int pa = (int)(tq & 0xFFFFFu), pb = (int)((tq >> 20) & 0xFFFFFu);
        const int e0a = __shfl(pa, rh, 64),     e0b = __shfl(pb, rh, 64);
        const int e1a = __shfl(pa, 8 + rh, 64), e1b = __shfl(pb, 8 + rh, 64);
        vA0 = *reinterpret_cast<const uint4*>(&xtab[(size_t)e0a * DD + cb]);
        vB0 = *reinterpret_cast<const uint4*>(&xtab[(size_t)e0b * DD + cb]);
        vA1 = *reinterpret_cast<const uint4*>(&xtab[(size_t)e1a * DD + cb]);
        vB1 = *reinterpret_cast<const uint4*>(&xtab[(size_t)e1b * DD + cb]);
    }

    for (int t0 = p0; t0 < p1; t0 += 16) {
        const int cnt = min(16, p1 - t0);
        const int pe  = (int)(tq >> 40);

        // issue next tile's tq load (latency hides under prod2+MFMA)
        const int tn = t0 + 16;
        u64 tqn = 0;
        if (tn < p1) tqn = tep[tn + min(lane & 15, (p1 - tn) - 1)];

        // ---- consume current gathers -> P tile ----
        {
            uint4 pk;
            pk.x = prod2(vA0.x, vB0.x); pk.y = prod2(vA0.y, vB0.y);
            pk.z = prod2(vA0.z, vB0.z); pk.w = prod2(vA0.w, vB0.w);
            int swz = (rh & 7) << 3;
            *reinterpret_cast<uint4*>(&P[w][rh * 64 + (cb ^ swz)]) = pk;
            pk.x = prod2(vA1.x, vB1.x); pk.y = prod2(vA1.y, vB1.y);
            pk.z = prod2(vA1.z, vB1.z); pk.w = prod2(vA1.w, vB1.w);
            const int ttl = 8 + rh;
            swz = (ttl & 7) << 3;
            *reinterpret_cast<uint4*>(&P[w][ttl * 64 + (cb ^ swz)]) = pk;
        }

        // ---- MFMA ----
        const int row = lane & 15;
        const int d0  = (lane >> 4) * 8;
        const int sw  = (row & 7) << 3;
        const bf16x8 a0 = *reinterpret_cast<const bf16x8*>(&P[w][row * 64 + ((d0)      ^ sw)]);
        const bf16x8 a1 = *reinterpret_cast<const bf16x8*>(&P[w][row * 64 + ((d0 + 32) ^ sw)]);

        f32x4 acc0 = {0.f, 0.f, 0.f, 0.f}, acc1 = acc0, acc2 = acc0, acc3 = acc0;
        MFMA8(bw, a0, a1)

        const int rb4 = (lane >> 4) * 4;
        const int cl  = lane & 15;
#pragma unroll
        for (int r = 0; r < 4; ++r) {
            M[w][(rb4 + r) * MST + cl + 0]  = fmaxf(acc0[r], 0.f);
            M[w][(rb4 + r) * MST + cl + 16] = fmaxf(acc1[r], 0.f);
            M[w][(rb4 + r) * MST + cl + 32] = fmaxf(acc2[r], 0.f);
            M[w][(rb4 + r) * MST + cl + 48] = fmaxf(acc3[r], 0.f);
        }

        // ---- issue NEXT tile's gathers (in flight across the reduce) ----
        if (tn < p1) {
            const int pa = (int)(tqn & 0xFFFFFu), pb = (int)((tqn >> 20) & 0xFFFFFu);
            const int e0a = __shfl(pa, rh, 64),     e0b = __shfl(pb, rh, 64);
            const int e1a = __shfl(pa, 8 + rh, 64), e1b = __shfl(pb, 8 + rh, 64);
            vA0 = *reinterpret_cast<const uint4*>(&xtab[(size_t)e0a * DD + cb]);
            vB0 = *reinterpret_cast<const uint4*>(&xtab[(size_t)e0b * DD + cb]);
            vA1 = *reinterpret_cast<const uint4*>(&xtab[(size_t)e1a * DD + cb]);
            vB1 = *reinterpret_cast<const uint4*>(&xtab[(size_t)e1b * DD + cb]);
        }

        // ---- run-length reduce (sorted => equal-e rows adjacent) ----
        for (int r = 0; r < cnt; ++r) {
            const int e_r = __builtin_amdgcn_readlane(pe, r);
            if (e_r != cur_e) {
                if (cur_e >= 0) {
                    if (!have_sv) { e_sv = cur_e; sum_sv = sum; have_sv = true; }
                    else aggbf[(size_t)cur_e * DD + lane] = f2bf(sum);  // exclusive owner
                }
                cur_e = e_r; sum = 0.f;
            }
            sum += M[w][r * MST + lane];
        }

        tq = tqn;
    }

    // ---- boundary edges -> pk-atomics onto rows pre-zeroed by lsort ----
    {
        const float nsum = __shfl_xor(sum, 1, 64);
        if (cur_e >= 0 && !(lane & 1))
            pk_atomic_add_bf16(&aggbf[(size_t)cur_e * DD + lane], pack2(sum, nsum));
        if (have_sv) {
            const float nsv = __shfl_xor(sum_sv, 1, 64);
            if (!(lane & 1))
                pk_atomic_add_bf16(&aggbf[(size_t)e_sv * DD + lane], pack2(sum_sv, nsv));
        }
    }
}

// ---------- update pass ----------
__global__ __launch_bounds__(256) void upd_fast(
    const unsigned short* __restrict__ xtab, const unsigned short* __restrict__ aggbf,
    const float* __restrict__ Wupd, float* __restrict__ out, int E_) {
    __shared__ unsigned short P[4][16 * 64];
    __shared__ float U[4][16 * MST];

    const int lane = threadIdx.x & 63;
    const int w    = threadIdx.x >> 6;

    bf16x8 bw[4][2];
    load_w_frags(Wupd, lane, bw);

    const int wave   = (blockIdx.x * blockDim.x + threadIdx.x) >> 6;
    const int nwaves = (gridDim.x * blockDim.x) >> 6;
    const int groups = E_ >> 4;

    for (int g = wave; g < groups; g += nwaves) {
        const int bu = g << 4;

#pragma unroll
        for (int half = 0; half < 2; ++half) {
            const int flat = half * 512 + lane * 8;
            const int row  = flat >> 6;
            const int colb = flat & 63;
            const uint4 v = *reinterpret_cast<const uint4*>(&aggbf[(size_t)bu * DD + flat]);
            *reinterpret_cast<uint4*>(&P[w][row * 64 + (colb ^ ((row & 7) << 3))]) = v;
        }

        const int row = lane & 15;
        const int d0  = (lane >> 4) * 8;
        const int sw  = (row & 7) << 3;
        const bf16x8 a0 = *reinterpret_cast<const bf16x8*>(&P[w][row * 64 + ((d0)      ^ sw)]);
        const bf16x8 a1 = *reinterpret_cast<const bf16x8*>(&P[w][row * 64 + ((d0 + 32) ^ sw)]);

        f32x4 acc0 = {0.f, 0.f, 0.f, 0.f}, acc1 = acc0, acc2 = acc0, acc3 = acc0;
        MFMA8(bw, a0, a1)

        const int rb4 = (lane >> 4) * 4;
        const int cl  = lane & 15;
#pragma unroll
        for (int r = 0; r < 4; ++r) {
            U[w][(rb4 + r) * MST + cl + 0]  = acc0[r];
            U[w][(rb4 + r) * MST + cl + 16] = acc1[r];
            U[w][(rb4 + r) * MST + cl + 32] = acc2[r];
            U[w][(rb4 + r) * MST + cl + 48] = acc3[r];
        }

#pragma unroll
        for (int tt = 0; tt < 16; ++tt) {
            const int e   = bu + tt;
            const float x = bf2f(xtab[(size_t)e * DD + lane]);
            out[(size_t)e * DD + lane] = fmaxf(x + U[w][tt * MST + lane], 0.f);
        }
    }
}

// ---------- tier 1: fully general fallback ----------
__global__ __launch_bounds__(256) void tri_fb(
    const float* __restrict__ feat, const float* __restrict__ emb,
    const float* __restrict__ Wmsg, const int* __restrict__ rel,
    const int* __restrict__ ab, const int* __restrict__ bc,
    const int* __restrict__ ac, float* __restrict__ agg, int T_) {
    __shared__ unsigned short P[4][16 * 64];
    const int lane = threadIdx.x & 63;
    const int w    = threadIdx.x >> 6;
    bf16x8 bw[4][2];
    load_w_frags(Wmsg, lane, bw);
    const int wave   = (blockIdx.x * blockDim.x + threadIdx.x) >> 6;
    const int nwaves = (gridDim.x * blockDim.x) >> 6;
    const int groups = (T_ + 15) >> 4;
    for (int g = wave; g < groups; g += nwaves) {
        const int bu = __builtin_amdgcn_readfirstlane(g << 4);
#pragma unroll 4
        for (int tt = 0; tt < 16; ++tt) {
            const int t = bu + tt;
            float p = 0.f;
            if (t < T_) {
                const int ea = ab[t], eb = bc[t];
                const float xa = feat[ea * DD + lane] + emb[rel[ea] * DD + lane];
                const float xb = feat[eb * DD + lane] + emb[rel[eb] * DD + lane];
                p = xa * xb;
            }
            P[w][tt * 64 + (lane ^ ((tt & 7) << 3))] = f2bf(p);
        }
        const int row = lane & 15;
        const int d0  = (lane >> 4) * 8;
        const int sw  = (row & 7) << 3;
        const bf16x8 a0 = *reinterpret_cast<const bf16x8*>(&P[w][row * 64 + ((d0)      ^ sw)]);
        const bf16x8 a1 = *reinterpret_cast<const bf16x8*>(&P[w][row * 64 + ((d0 + 32) ^ sw)]);
        f32x4 acc0 = {0.f, 0.f, 0.f, 0.f}, acc1 = acc0, acc2 = acc0, acc3 = acc0;
        MFMA8(bw, a0, a1)
        const int rb4 = (lane >> 4) * 4;
        const int cl  = lane & 15;
#pragma unroll
        for (int r = 0; r < 4; ++r) {
            const int t = bu + rb4 + r;
            if (t < T_) {
                float* dst = &agg[(size_t)ac[t] * DD + cl];
                atomicAdd(dst + 0,  fmaxf(acc0[r], 0.f));
                atomicAdd(dst + 16, fmaxf(acc1[r], 0.f));
                atomicAdd(dst + 32, fmaxf(acc2[r], 0.f));
                atomicAdd(dst + 48, fmaxf(acc3[r], 0.f));
            }
        }
    }
}

__global__ __launch_bounds__(256) void upd_fb(
    const float* __restrict__ feat, const float* __restrict__ emb,
    const float* __restrict__ Wupd, const int* __restrict__ rel,
    float* __restrict__ agg_out, int E_) {
    __shared__ unsigned short P[4][16 * 64];
    __shared__ float U[4][16 * MST];
    const int lane = threadIdx.x & 63;
    const int w    = threadIdx.x >> 6;
    bf16x8 bw[4][2];
    load_w_frags(Wupd, lane, bw);
    const int wave   = (blockIdx.x * blockDim.x + threadIdx.x) >> 6;
    const int nwaves = (gridDim.x * blockDim.x) >> 6;
    const int groups = (E_ + 15) >> 4;
    for (int g = wave; g < groups; g += nwaves) {
        const int bu = __builtin_amdgcn_readfirstlane(g << 4);
#pragma unroll 4
        for (int tt = 0; tt < 16; ++tt) {
            const int e = bu + tt;
            const float v = (e < E_) ? agg_out[(size_t)e * DD + lane] : 0.f;
            P[w][tt * 64 + (lane ^ ((tt & 7) << 3))] = f2bf(v);
        }
        const int row = lane & 15;
        const int d0  = (lane >> 4) * 8;
        const int sw  = (row & 7) << 3;
        const bf16x8 a0 = *reinterpret_cast<const bf16x8*>(&P[w][row * 64 + ((d0)      ^ sw)]);
        const bf16x8 a1 = *reinterpret_cast<const bf16x8*>(&P[w][row * 64 + ((d0 + 32) ^ sw)]);
        f32x4 acc0 = {0.f, 0.f, 0.f, 0.f}, acc1 = acc0, acc2 = acc0, acc3 = acc0;
        MFMA8(bw, a0, a1)
        const int rb4 = (lane >> 4) * 4;
        const int cl  = lane & 15;
#pragma unroll
        for (int r = 0; r < 4; ++r) {
            U[w][(rb4 + r) * MST + cl + 0]  = acc0[r];
            U[w][(rb4 + r) * MST + cl + 16] = acc1[r];
            U[w][(rb4 + r) * MST + cl + 32] = acc2[r];
            U[w][(rb4 + r) * MST + cl + 48] = acc3[r];
        }
#pragma unroll 4
        for (int tt = 0; tt < 16; ++tt) {
            const int e = bu + tt;
            if (e < E_) {
                const float x = feat[(size_t)e * DD + lane] + emb[rel[e] * DD + lane];
                agg_out[(size_t)e * DD + lane] = fmaxf(x + U[w][tt * MST + lane], 0.f);
            }
        }
    }
}

extern "C" void kernel_launch(void* const* d_in, const int* in_sizes, int n_in,
                              void* d_out, int out_size, void* d_ws, size_t ws_size,
                              hipStream_t stream) {
    const float* feat = (const float*)d_in[0];
    const float* emb  = (const float*)d_in[1];
    const float* Wmsg = (const float*)d_in[2];
    const float* Wupd = (const float*)d_in[3];
    const int*   rel  = (const int*)d_in[4];
    const int*   ab   = (const int*)d_in[5];
    const int*   bc   = (const int*)d_in[6];
    const int*   ac   = (const int*)d_in[7];

    const int E_ = in_sizes[0] / DD;
    const int T_ = in_sizes[5];

    const int    NBUK   = (E_ + (1 << BUK_BITS) - 1) >> BUK_BITS;      // <= 256
    const int    ntab   = NBUK * NBLK_P;
    const int    nblk_s = (ntab + SCAN_CH - 1) / SCAN_CH;
    const size_t xbytes = (size_t)E_ * DD * sizeof(unsigned short);    // 128 MB
    const size_t tbytes = (size_t)T_ * sizeof(u64);                    // 16 MB
    const size_t gbytes = ((size_t)ntab * sizeof(unsigned int) + 255u) & ~(size_t)255u;
    const size_t need   = 2 * xbytes + 2 * tbytes + 2 * gbytes + 4096 * sizeof(unsigned int);

    const bool fast = (E_ <= (1 << 20)) && ((E_ & 15) == 0) && (NBUK <= 256) &&
                      (nblk_s <= 1024) && (ws_size >= need);

    if (fast) {
        char* p = (char*)d_ws;
        unsigned short* xtab  = (unsigned short*)p;  p += xbytes;
        unsigned short* aggbf = (unsigned short*)p;  p += xbytes;
        u64*            tep   = (u64*)p;             p += tbytes;
        u64*            teps  = (u64*)p;             p += tbytes;
        unsigned int*   gtabC = (unsigned int*)p;    p += gbytes;
        unsigned int*   gtabO = (unsigned int*)p;    p += gbytes;
        unsigned int*   bsum  = (unsigned int*)p;

        const int chunk  = (T_ + NBLK_P - 1) / NBLK_P;
        const int nwaves = 2048 * 256 / 64;          // 8192 waves (round-12 config)
        int S = (T_ + nwaves - 1) / nwaves;
        S = (S + 15) & ~15;

        hipLaunchKernelGGL(xprep_kernel, dim3(2048), dim3(256), 0, stream,
                           (const float4*)feat, (const float4*)emb, rel, xtab, E_ * 16);
        hipLaunchKernelGGL(histc_kernel, dim3(NBLK_P), dim3(256), 0, stream,
                           ac, gtabC, T_, chunk, NBUK);
        hipLaunchKernelGGL(scanA_kernel, dim3(nblk_s), dim3(256), 0, stream, gtabC, bsum, ntab);
        hipLaunchKernelGGL(scanB_kernel, dim3(1), dim3(1024), 0, stream, bsum, nblk_s);
        hipLaunchKernelGGL(scanC_kernel, dim3(nblk_s), dim3(256), 0, stream,
                           gtabC, bsum, gtabO, ntab);
        hipLaunchKernelGGL(part_kernel, dim3(NBLK_P), dim3(256), 0, stream,
                           ab, bc, ac, gtabO, tep, T_, chunk, NBUK);
        hipLaunchKernelGGL(lsort_kernel, dim3(NBUK), dim3(256), 0, stream,
                           tep, gtabO, teps, aggbf, T_, NBUK, E_, S);
        hipLaunchKernelGGL(tri_csr6_kernel, dim3(2048), dim3(256), 0, stream,
                           xtab, Wmsg, teps, aggbf, T_, S);
        hipLaunchKernelGGL(upd_fast, dim3(2048), dim3(256), 0, stream,
                           xtab, aggbf, Wupd, (float*)d_out, E_);
    } else {
        float* agg = (float*)d_out;
        hipMemsetAsync(d_out, 0, (size_t)E_ * DD * sizeof(float), stream);
        hipLaunchKernelGGL(tri_fb, dim3(2048), dim3(256), 0, stream,
                           feat, emb, Wmsg, rel, ab, bc, ac, agg, T_);
        hipLaunchKernelGGL(upd_fb, dim3(2048), dim3(256), 0, stream,
                           feat, emb, Wupd, rel, agg, E_);
    }
}